// Round 2
// baseline (1408.150 us; speedup 1.0000x reference)
//
#include <hip/hip_runtime.h>
#include <hip/hip_bf16.h>

// Problem constants (B=1)
#define CL 2048   // sequence length
#define CD 1024   // hidden
#define CH 16     // heads
#define CHD 64    // head dim
#define TQ 4      // query rows per workgroup in attention

__device__ __forceinline__ float wave_sum(float x) {
#pragma unroll
  for (int m = 32; m >= 1; m >>= 1) x += __shfl_xor(x, m, 64);
  return x;  // all 64 lanes hold the identical total
}

// C[M,N] = A[M,K] * B[N,K]^T, all fp32 (torch Linear: y = x W^T).
// 64x64 tile per 256-thread block; thread (tx,ty) computes a 4x4 micro-tile.
// A,B staged k-major in LDS so fragment reads are ds_read_b128.
__global__ __launch_bounds__(256) void gemm_f32_bt(
    const float* __restrict__ A, const float* __restrict__ B,
    float* __restrict__ C, int M, int N, int K) {
  __shared__ float As[64][68];  // [k][m]; pad 68 keeps rows 16B-aligned for b128
  __shared__ float Bs[64][68];  // [k][n]
  const int tid = threadIdx.x;
  const int tx = tid & 15, ty = tid >> 4;
  const int m0 = blockIdx.y * 64, n0 = blockIdx.x * 64;

  float acc[4][4];
#pragma unroll
  for (int i = 0; i < 4; i++)
#pragma unroll
    for (int j = 0; j < 4; j++) acc[i][j] = 0.f;

  for (int k0 = 0; k0 < K; k0 += 64) {
    // Stage 64(k) x 64(row) tiles: global reads coalesced along k (c),
    // LDS writes at stride 68 -> bank (4c+r)%32, ~8-way, only 16 writes/thread.
#pragma unroll
    for (int i = 0; i < 16; i++) {
      int idx = i * 256 + tid;
      int r = idx >> 6, c = idx & 63;
      As[c][r] = A[(size_t)(m0 + r) * K + k0 + c];
      Bs[c][r] = B[(size_t)(n0 + r) * K + k0 + c];
    }
    __syncthreads();
#pragma unroll 8
    for (int kk = 0; kk < 64; kk++) {
      const float4 av = *reinterpret_cast<const float4*>(&As[kk][ty * 4]);
      const float4 bv = *reinterpret_cast<const float4*>(&Bs[kk][tx * 4]);
      const float a4[4] = {av.x, av.y, av.z, av.w};
      const float b4[4] = {bv.x, bv.y, bv.z, bv.w};
#pragma unroll
      for (int i = 0; i < 4; i++)
#pragma unroll
        for (int j = 0; j < 4; j++) acc[i][j] = fmaf(a4[i], b4[j], acc[i][j]);
    }
    __syncthreads();
  }

#pragma unroll
  for (int i = 0; i < 4; i++) {
    float4 o = {acc[i][0], acc[i][1], acc[i][2], acc[i][3]};
    *reinterpret_cast<float4*>(&C[(size_t)(m0 + ty * 4 + i) * N + n0 + tx * 4]) = o;
  }
}

// One workgroup = (head h, TQ=4 consecutive query rows). Wave w owns row q0+w.
// Phase 1: scores (fp32 dots, K tiles staged in LDS) -> S[4][2048].
// Phase 2: Michelot fixed-point -> k_support (== reference's sort-based count);
//          reference quirk: tau_star = (FULL row sum - 1)/k_support.
// Phase 3: out = p @ V (V tiles staged in same LDS buffer as K).
__global__ __launch_bounds__(256) void attn_entmax(
    const float* __restrict__ q, const float* __restrict__ k,
    const float* __restrict__ v, float* __restrict__ o) {
  __shared__ float S[TQ][CL];     // 32 KB scores -> p
  __shared__ float Qs[TQ][CHD];   // 1 KB
  __shared__ float KV[64][65];    // 16.6 KB; pad 65: (65*r+c)%32=(r+c)%32 patterns free

  const int tid  = threadIdx.x;
  const int lane = tid & 63;
  const int wave = tid >> 6;
  const int h    = blockIdx.y;
  const int q0   = blockIdx.x * TQ;
  const int col0 = h * CHD;

  Qs[wave][lane] = q[(size_t)(q0 + wave) * CD + col0 + lane];
  __syncthreads();

  const int nmax   = q0 + TQ;
  const int ntiles = (nmax + 63) >> 6;
  const int n      = q0 + wave + 1;   // causal: valid columns for this wave's row

  // ---- Phase 1: scores ----
  for (int jt = 0; jt < ntiles; jt++) {
    const int j0 = jt << 6;
#pragma unroll
    for (int it = 0; it < 16; it++) {          // stage 64x64 fp32 K tile
      int jr = it * 4 + wave;
      KV[jr][lane] = k[(size_t)(j0 + jr) * CD + col0 + lane];
    }
    __syncthreads();
    float a = 0.f;
#pragma unroll
    for (int kk = 0; kk < CHD; kk++)
      a = fmaf(Qs[wave][kk], KV[lane][kk], a);  // Qs broadcast; KV 2-way (free)
    S[wave][j0 + lane] = a * 0.125f;            // 2^-3 scale: exact
    __syncthreads();
  }

  // ---- Phase 2: entmax per row ----
  float ssum = 0.f;
  for (int j = lane; j < n; j += 64) ssum += S[wave][j];
  ssum = wave_sum(ssum);

  // Michelot: tau <- (sum_{s>tau} s - 1)/#{s>tau}; support shrinks monotonically
  // to the sparsemax support. max(s) > tau always => count >= 1 (no div by 0).
  float tau = (ssum - 1.f) / (float)n;
  int cnt = n;
  for (int it = 0; it < 1024; it++) {
    float cs = 0.f, cn = 0.f;
    for (int j = lane; j < n; j += 64) {
      float s = S[wave][j];
      if (s > tau) { cs += s; cn += 1.f; }
    }
    cs = wave_sum(cs);
    cn = wave_sum(cn);
    int newcnt = (int)cn;
    tau = (cs - 1.f) / cn;
    if (newcnt == cnt) break;
    cnt = newcnt;
  }

  // Reference quirk: tau_star uses the FULL masked row sum, not the top-k sum.
  const float tau_star = (ssum - 1.f) / (float)cnt;
  float psum = 0.f;
  for (int j = lane; j < n; j += 64) {
    float p = S[wave][j] - tau_star;
    p = p > 0.f ? p : 0.f;
    S[wave][j] = p;
    psum += p;
  }
  psum = wave_sum(psum);
  const float inv = 1.f / (psum + 1e-10f);
  __syncthreads();   // S writes done before anyone proceeds; KV about to be reused

  // ---- Phase 3: p @ V ----
  float acc = 0.f;
  for (int jt = 0; jt < ntiles; jt++) {
    const int j0 = jt << 6;
#pragma unroll
    for (int it = 0; it < 16; it++) {          // stage 64x64 fp32 V tile
      int jr = it * 4 + wave;
      KV[jr][lane] = v[(size_t)(j0 + jr) * CD + col0 + lane];
    }
    __syncthreads();
    int lim = n - j0;
    lim = lim > 64 ? 64 : lim;                  // <=0 for done rows: loop skipped
    for (int j = 0; j < lim; j++)
      acc = fmaf(S[wave][j0 + j], KV[j][lane], acc);  // KV[j][lane]: conflict-free
    __syncthreads();
  }
  o[(size_t)(q0 + wave) * CD + col0 + lane] = acc * inv;
}

extern "C" void kernel_launch(void* const* d_in, const int* in_sizes, int n_in,
                              void* d_out, int out_size, void* d_ws, size_t ws_size,
                              hipStream_t stream) {
  const float* x  = (const float*)d_in[0];
  const float* Wq = (const float*)d_in[1];
  const float* Wk = (const float*)d_in[2];
  const float* Wv = (const float*)d_in[3];
  const float* Wo = (const float*)d_in[4];
  float* out = (float*)d_out;

  // Workspace: 4 x 8 MB fp32
  float* qf = (float*)d_ws;
  float* kf = qf + (size_t)CL * CD;
  float* vf = kf + (size_t)CL * CD;
  float* of = vf + (size_t)CL * CD;

  dim3 gg(CD / 64, CL / 64);  // (16, 32)
  gemm_f32_bt<<<gg, 256, 0, stream>>>(x, Wq, qf, CL, CD, CD);
  gemm_f32_bt<<<gg, 256, 0, stream>>>(x, Wk, kf, CL, CD, CD);
  gemm_f32_bt<<<gg, 256, 0, stream>>>(x, Wv, vf, CL, CD, CD);
  attn_entmax<<<dim3(CL / TQ, CH), 256, 0, stream>>>(qf, kf, vf, of);
  gemm_f32_bt<<<gg, 256, 0, stream>>>(of, Wo, out, CL, CD, CD);
}

// Round 3
// 1000.970 us; speedup vs baseline: 1.4068x; 1.4068x over previous
//
#include <hip/hip_runtime.h>
#include <hip/hip_bf16.h>

// Problem constants (B=1)
#define CL 2048   // sequence length
#define CD 1024   // hidden
#define CH 16     // heads
#define CHD 64    // head dim
#define NEGS -1e30f

typedef __attribute__((ext_vector_type(8))) short short8;  // 8 x bf16 frag
typedef __attribute__((ext_vector_type(4))) float f32x4;

__device__ __forceinline__ float wave_sum(float x) {
#pragma unroll
  for (int m = 32; m >= 1; m >>= 1) x += __shfl_xor(x, m, 64);
  return x;  // all 64 lanes hold the total
}

// Broadcast lane `l` of v to all lanes (scalar pipe, NOT the LDS pipe).
__device__ __forceinline__ float rl_f(float v, int l) {
  return __int_as_float(__builtin_amdgcn_readlane(__float_as_int(v), l));
}

// fp32 -> (hi, lo) bf16 planes: x ~= hi + lo to ~16 mantissa bits.
__global__ __launch_bounds__(256) void split_bf16(
    const float* __restrict__ x, short* __restrict__ hi, short* __restrict__ lo,
    int n4) {
  const int i = blockIdx.x * 256 + threadIdx.x;
  if (i >= n4) return;
  const float4 v = reinterpret_cast<const float4*>(x)[i];
  const float vv[4] = {v.x, v.y, v.z, v.w};
  short hh[4], ll[4];
#pragma unroll
  for (int e = 0; e < 4; e++) {
    __hip_bfloat16 bh = __float2bfloat16(vv[e]);
    float r = vv[e] - __bfloat162float(bh);
    __hip_bfloat16 bl = __float2bfloat16(r);
    hh[e] = __builtin_bit_cast(short, bh);
    ll[e] = __builtin_bit_cast(short, bl);
  }
  reinterpret_cast<short4*>(hi)[i] = make_short4(hh[0], hh[1], hh[2], hh[3]);
  reinterpret_cast<short4*>(lo)[i] = make_short4(ll[0], ll[1], ll[2], ll[3]);
}

// C[M,N] = (Ah+Al)(M,K) * (Bh+Bl)(N,K)^T via 3-term split-bf16 MFMA (~fp32 acc).
// WG 256 thr = 4 waves in 2x2; wave tile 32x32 = 2x2 MFMA 16x16x32.
// Frags loaded directly from global (K-major, 16B/lane); layout per guide S3:
// A[m=l15+16i][k=quad*8+j], C: col=l15, row=quad*4+reg (m89/m91-verified).
__global__ __launch_bounds__(256) void gemm_split_bt(
    const short* __restrict__ Ah, const short* __restrict__ Al,
    const short* __restrict__ Bh, const short* __restrict__ Bl,
    float* __restrict__ C, int M, int N, int K) {
  const int lane = threadIdx.x & 63, wave = threadIdx.x >> 6;
  const int l15 = lane & 15, quad = lane >> 4;
  const int m_base = blockIdx.y * 64 + (wave >> 1) * 32;
  const int n_base = blockIdx.x * 64 + (wave & 1) * 32;

  f32x4 acc[2][2];
#pragma unroll
  for (int i = 0; i < 2; i++)
#pragma unroll
    for (int j = 0; j < 2; j++) acc[i][j] = {0.f, 0.f, 0.f, 0.f};

  const size_t aoff = (size_t)(m_base + l15) * K + quad * 8;
  const size_t boff = (size_t)(n_base + l15) * K + quad * 8;

  for (int k0 = 0; k0 < K; k0 += 32) {
    short8 ah[2], al[2], bh[2], bl[2];
#pragma unroll
    for (int i = 0; i < 2; i++) {
      const size_t ai = aoff + (size_t)i * 16 * K + k0;
      const size_t bi = boff + (size_t)i * 16 * K + k0;
      ah[i] = *reinterpret_cast<const short8*>(Ah + ai);
      al[i] = *reinterpret_cast<const short8*>(Al + ai);
      bh[i] = *reinterpret_cast<const short8*>(Bh + bi);
      bl[i] = *reinterpret_cast<const short8*>(Bl + bi);
    }
#pragma unroll
    for (int im = 0; im < 2; im++)
#pragma unroll
      for (int in = 0; in < 2; in++) {
        acc[im][in] = __builtin_amdgcn_mfma_f32_16x16x32_bf16(ah[im], bl[in], acc[im][in], 0, 0, 0);
        acc[im][in] = __builtin_amdgcn_mfma_f32_16x16x32_bf16(al[im], bh[in], acc[im][in], 0, 0, 0);
        acc[im][in] = __builtin_amdgcn_mfma_f32_16x16x32_bf16(ah[im], bh[in], acc[im][in], 0, 0, 0);
      }
  }

#pragma unroll
  for (int im = 0; im < 2; im++)
#pragma unroll
    for (int in = 0; in < 2; in++)
#pragma unroll
      for (int r = 0; r < 4; r++)
        C[(size_t)(m_base + im * 16 + quad * 4 + r) * N + n_base + in * 16 + l15] =
            acc[im][in][r];
}

// Per-row entmax on register-resident scores s[0..31] (col = 64t + lane).
// Invalid entries hold NEGS. Returns 1/(psum+1e-10); overwrites s with p.
// Arithmetic order is bit-identical to the round-2 passing version.
__device__ __forceinline__ float entmax_row(float (&s)[32], int n) {
  float ssum = 0.f;
#pragma unroll
  for (int t = 0; t < 32; t++)
    if (s[t] > -1e29f) ssum += s[t];
  ssum = wave_sum(ssum);

  float tau = (ssum - 1.f) / (float)n;
  int cnt = n;
  for (int it = 0; it < 1024; it++) {
    float cs = 0.f, cn = 0.f;
#pragma unroll
    for (int t = 0; t < 32; t++) {
      const float sv = s[t];
      if (sv > tau) { cs += sv; cn += 1.f; }   // NEGS never > tau
    }
    cs = wave_sum(cs);
    cn = wave_sum(cn);
    const int newcnt = (int)cn;
    tau = (cs - 1.f) / cn;
    if (newcnt == cnt) break;
    cnt = newcnt;
  }

  // Reference quirk: tau_star uses the FULL masked row sum, not the top-k sum.
  const float tau_star = (ssum - 1.f) / (float)cnt;
  float psum = 0.f;
#pragma unroll
  for (int t = 0; t < 32; t++) {
    float p = s[t] - tau_star;   // NEGS -> huge negative -> p=0
    p = p > 0.f ? p : 0.f;
    s[t] = p;
    psum += p;
  }
  psum = wave_sum(psum);
  return 1.f / (psum + 1e-10f);
}

// WG = 512 thr (8 waves) x (head h, 16 query rows). Wave w owns rows q0+2w, +1.
// Scores/p live in 64 VGPRs per lane (statically unrolled tile loops).
// Q broadcast via v_readlane (scalar pipe) -> each KT ds_read_b128 feeds 8 FMAs.
__global__ __launch_bounds__(512) void attn_entmax2(
    const float* __restrict__ q, const float* __restrict__ k,
    const float* __restrict__ v, short* __restrict__ oh, short* __restrict__ ol) {
  __shared__ float KT[64][68];  // 17.4 KB; stride 68 floats = 17x16B (aligned, low conflict)

  const int tid = threadIdx.x, lane = tid & 63, wave = tid >> 6;
  const int h = blockIdx.y, q0 = blockIdx.x * 16;
  const int col0 = h * CHD;
  const int row0 = q0 + wave * 2, row1 = row0 + 1;
  const int ntiles = (q0 + 79) >> 6;  // covers cols 0..q0+15 (WG-uniform)

  const float qr0 = q[(size_t)row0 * CD + col0 + lane];  // Q[row][lane]
  const float qr1 = q[(size_t)row1 * CD + col0 + lane];

  float s0[32], s1[32];

  // ---- Phase 1: scores ----
#pragma unroll
  for (int jt = 0; jt < 32; jt++) {
    if (jt < ntiles) {
      const int j0 = jt * 64;
#pragma unroll
      for (int i = 0; i < 2; i++) {  // stage 64x64 fp32 K tile, b128 in/out
        const int fidx = i * 512 + tid;
        const int jr = fidx >> 4, c4 = (fidx & 15) * 4;
        *reinterpret_cast<float4*>(&KT[jr][c4]) =
            *reinterpret_cast<const float4*>(&k[(size_t)(j0 + jr) * CD + col0 + c4]);
      }
      __syncthreads();
      float a0 = 0.f, a1 = 0.f;
#pragma unroll
      for (int c = 0; c < 16; c++) {
        const float4 kv = *reinterpret_cast<const float4*>(&KT[lane][c * 4]);
        const float ke[4] = {kv.x, kv.y, kv.z, kv.w};
#pragma unroll
        for (int e = 0; e < 4; e++) {  // kk ascending: same order as round 2
          a0 = fmaf(rl_f(qr0, c * 4 + e), ke[e], a0);
          a1 = fmaf(rl_f(qr1, c * 4 + e), ke[e], a1);
        }
      }
      const int col = j0 + lane;
      s0[jt] = (col <= row0) ? a0 * 0.125f : NEGS;
      s1[jt] = (col <= row1) ? a1 * 0.125f : NEGS;
      __syncthreads();
    } else {
      s0[jt] = NEGS;
      s1[jt] = NEGS;
    }
  }

  // ---- Phase 2: entmax (registers + wave shuffles only) ----
  const float inv0 = entmax_row(s0, row0 + 1);
  const float inv1 = entmax_row(s1, row1 + 1);

  // ---- Phase 3: p @ V ----
  float acc0 = 0.f, acc1 = 0.f;
#pragma unroll
  for (int jt = 0; jt < 32; jt++) {
    if (jt < ntiles) {
      const int j0 = jt * 64;
#pragma unroll
      for (int i = 0; i < 2; i++) {  // stage 64x64 fp32 V tile
        const int fidx = i * 512 + tid;
        const int jr = fidx >> 4, c4 = (fidx & 15) * 4;
        *reinterpret_cast<float4*>(&KT[jr][c4]) =
            *reinterpret_cast<const float4*>(&v[(size_t)(j0 + jr) * CD + col0 + c4]);
      }
      __syncthreads();
      int lim = row1 - j0 + 1;              // wave-uniform; p==0 pads row0's tail
      lim = lim < 0 ? 0 : (lim > 64 ? 64 : lim);
      for (int j = 0; j < lim; j++) {
        const float vv = KT[j][lane];       // row broadcast: conflict-free
        acc0 = fmaf(rl_f(s0[jt], j), vv, acc0);
        acc1 = fmaf(rl_f(s1[jt], j), vv, acc1);
      }
      __syncthreads();
    }
  }

  // ---- Epilogue: split o into bf16 hi/lo planes for the MFMA O-GEMM ----
  const float o0 = acc0 * inv0, o1 = acc1 * inv1;
  {
    __hip_bfloat16 bh = __float2bfloat16(o0);
    __hip_bfloat16 bl = __float2bfloat16(o0 - __bfloat162float(bh));
    oh[(size_t)row0 * CD + col0 + lane] = __builtin_bit_cast(short, bh);
    ol[(size_t)row0 * CD + col0 + lane] = __builtin_bit_cast(short, bl);
  }
  {
    __hip_bfloat16 bh = __float2bfloat16(o1);
    __hip_bfloat16 bl = __float2bfloat16(o1 - __bfloat162float(bh));
    oh[(size_t)row1 * CD + col0 + lane] = __builtin_bit_cast(short, bh);
    ol[(size_t)row1 * CD + col0 + lane] = __builtin_bit_cast(short, bl);
  }
}

extern "C" void kernel_launch(void* const* d_in, const int* in_sizes, int n_in,
                              void* d_out, int out_size, void* d_ws, size_t ws_size,
                              hipStream_t stream) {
  const float* x  = (const float*)d_in[0];
  const float* Wq = (const float*)d_in[1];
  const float* Wk = (const float*)d_in[2];
  const float* Wv = (const float*)d_in[3];
  const float* Wo = (const float*)d_in[4];
  float* out = (float*)d_out;

  // Workspace layout (56 MB total)
  char* ws = (char*)d_ws;
  float* qf  = (float*)(ws + (0ull  << 20));  // 8 MB fp32 q
  float* kf  = (float*)(ws + (8ull  << 20));  // 8 MB fp32 k
  float* vf  = (float*)(ws + (16ull << 20));  // 8 MB fp32 v
  short* xh  = (short*)(ws + (24ull << 20));  // 4 MB
  short* xl  = (short*)(ws + (28ull << 20));  // 4 MB
  short* wqh = (short*)(ws + (32ull << 20));  // 2 MB each below
  short* wql = (short*)(ws + (34ull << 20));
  short* wkh = (short*)(ws + (36ull << 20));
  short* wkl = (short*)(ws + (38ull << 20));
  short* wvh = (short*)(ws + (40ull << 20));
  short* wvl = (short*)(ws + (42ull << 20));
  short* woh = (short*)(ws + (44ull << 20));
  short* wol = (short*)(ws + (46ull << 20));
  short* oh  = (short*)(ws + (48ull << 20));  // 4 MB
  short* ol  = (short*)(ws + (52ull << 20));  // 4 MB

  // Split fp32 inputs into bf16 hi/lo planes
  split_bf16<<<2048, 256, 0, stream>>>(x,  xh,  xl,  (CL * CD) / 4);
  split_bf16<<<1024, 256, 0, stream>>>(Wq, wqh, wql, (CD * CD) / 4);
  split_bf16<<<1024, 256, 0, stream>>>(Wk, wkh, wkl, (CD * CD) / 4);
  split_bf16<<<1024, 256, 0, stream>>>(Wv, wvh, wvl, (CD * CD) / 4);
  split_bf16<<<1024, 256, 0, stream>>>(Wo, woh, wol, (CD * CD) / 4);

  dim3 gg(CD / 64, CL / 64);  // (16, 32) = 512 WGs
  gemm_split_bt<<<gg, 256, 0, stream>>>(xh, xl, wqh, wql, qf, CL, CD, CD);
  gemm_split_bt<<<gg, 256, 0, stream>>>(xh, xl, wkh, wkl, kf, CL, CD, CD);
  gemm_split_bt<<<gg, 256, 0, stream>>>(xh, xl, wvh, wvl, vf, CL, CD, CD);

  attn_entmax2<<<dim3(CL / 16, CH), 512, 0, stream>>>(qf, kf, vf, oh, ol);

  gemm_split_bt<<<gg, 256, 0, stream>>>(oh, ol, woh, wol, out, CL, CD, CD);
}

// Round 4
// 812.948 us; speedup vs baseline: 1.7322x; 1.2313x over previous
//
#include <hip/hip_runtime.h>
#include <hip/hip_bf16.h>

// Problem constants (B=1)
#define CL 2048   // sequence length
#define CD 1024   // hidden
#define CH 16     // heads
#define CHD 64    // head dim
#define NEGS -1e30f

typedef __attribute__((ext_vector_type(8))) short short8;  // 8 x bf16 frag
typedef __attribute__((ext_vector_type(4))) float f32x4;

__device__ __forceinline__ float wave_sum(float x) {
#pragma unroll
  for (int m = 32; m >= 1; m >>= 1) x += __shfl_xor(x, m, 64);
  return x;  // all 64 lanes hold the total
}

// Broadcast lane `l` of v to all lanes (VALU v_readlane, not the LDS pipe).
__device__ __forceinline__ float rl_f(float v, int l) {
  return __int_as_float(__builtin_amdgcn_readlane(__float_as_int(v), l));
}

// fp32 -> (hi, lo) bf16 planes: x ~= hi + lo to ~16 mantissa bits.
__global__ __launch_bounds__(256) void split_bf16(
    const float* __restrict__ x, short* __restrict__ hi, short* __restrict__ lo,
    int n4) {
  const int i = blockIdx.x * 256 + threadIdx.x;
  if (i >= n4) return;
  const float4 v = reinterpret_cast<const float4*>(x)[i];
  const float vv[4] = {v.x, v.y, v.z, v.w};
  short hh[4], ll[4];
#pragma unroll
  for (int e = 0; e < 4; e++) {
    __hip_bfloat16 bh = __float2bfloat16(vv[e]);
    float r = vv[e] - __bfloat162float(bh);
    __hip_bfloat16 bl = __float2bfloat16(r);
    hh[e] = __builtin_bit_cast(short, bh);
    ll[e] = __builtin_bit_cast(short, bl);
  }
  reinterpret_cast<short4*>(hi)[i] = make_short4(hh[0], hh[1], hh[2], hh[3]);
  reinterpret_cast<short4*>(lo)[i] = make_short4(ll[0], ll[1], ll[2], ll[3]);
}

// C[2048,1024] = (Ah+Al) * (B?h+B?l)^T via 3-term split-bf16 MFMA, fp32 out.
// m97-style: 128x128 tile/WG, LDS-staged BK=32, 4 waves (2x2), wave tile 64x64
// = 4x4 MFMA 16x16x32. B/C selected by blockIdx.x>>3 (QKV fusion; Wo: grid.x=8).
// Frag layout (m89/m91-verified): A[m=l15+16i][k=quad*8+j]; C col=l15,row=quad*4+r.
__global__ __launch_bounds__(256, 2) void gemm128_split(
    const short* __restrict__ Ah, const short* __restrict__ Al,
    const short* __restrict__ B0h, const short* __restrict__ B0l,
    const short* __restrict__ B1h, const short* __restrict__ B1l,
    const short* __restrict__ B2h, const short* __restrict__ B2l,
    float* __restrict__ C0, float* __restrict__ C1, float* __restrict__ C2) {
  __shared__ short AhS[128][32], AlS[128][32], BhS[128][32], BlS[128][32];
  const int tid = threadIdx.x, lane = tid & 63, wave = tid >> 6;
  const int l15 = lane & 15, quad = lane >> 4;
  const int sel = blockIdx.x >> 3, nb = blockIdx.x & 7;
  const short* Bh = sel == 0 ? B0h : (sel == 1 ? B1h : B2h);
  const short* Bl = sel == 0 ? B0l : (sel == 1 ? B1l : B2l);
  float* C = sel == 0 ? C0 : (sel == 1 ? C1 : C2);
  const int m0 = blockIdx.y * 128, n0 = nb * 128;
  const int wm = (wave >> 1) * 64, wn = (wave & 1) * 64;

  f32x4 acc[4][4];
#pragma unroll
  for (int i = 0; i < 4; i++)
#pragma unroll
    for (int j = 0; j < 4; j++) acc[i][j] = {0.f, 0.f, 0.f, 0.f};

  // Staging: wave p owns plane p (Ah/Al/Bh/Bl), 8 KB each per k-step.
  const short* gsrc = wave == 0 ? Ah : wave == 1 ? Al : wave == 2 ? Bh : Bl;
  short(*ldst)[32] = wave == 0 ? AhS : wave == 1 ? AlS : wave == 2 ? BhS : BlS;
  const int srow0 = (wave < 2) ? m0 : n0;

  for (int k0 = 0; k0 < CD; k0 += 32) {
#pragma unroll
    for (int i = 0; i < 8; i++) {
      const int ci = i * 64 + lane;        // 0..511 16B-chunks
      const int r = ci >> 2, kc = (ci & 3) * 8;
      *reinterpret_cast<short8*>(&ldst[r][kc]) =
          *reinterpret_cast<const short8*>(&gsrc[(size_t)(srow0 + r) * CD + k0 + kc]);
    }
    __syncthreads();
    short8 a_h[4], a_l[4], b_h[4], b_l[4];
#pragma unroll
    for (int i = 0; i < 4; i++) {
      a_h[i] = *reinterpret_cast<const short8*>(&AhS[wm + i * 16 + l15][quad * 8]);
      a_l[i] = *reinterpret_cast<const short8*>(&AlS[wm + i * 16 + l15][quad * 8]);
      b_h[i] = *reinterpret_cast<const short8*>(&BhS[wn + i * 16 + l15][quad * 8]);
      b_l[i] = *reinterpret_cast<const short8*>(&BlS[wn + i * 16 + l15][quad * 8]);
    }
#pragma unroll
    for (int im = 0; im < 4; im++)
#pragma unroll
      for (int in = 0; in < 4; in++) {  // same term order as round 3 (numerics)
        acc[im][in] = __builtin_amdgcn_mfma_f32_16x16x32_bf16(a_h[im], b_l[in], acc[im][in], 0, 0, 0);
        acc[im][in] = __builtin_amdgcn_mfma_f32_16x16x32_bf16(a_l[im], b_h[in], acc[im][in], 0, 0, 0);
        acc[im][in] = __builtin_amdgcn_mfma_f32_16x16x32_bf16(a_h[im], b_h[in], acc[im][in], 0, 0, 0);
      }
    __syncthreads();
  }

#pragma unroll
  for (int im = 0; im < 4; im++)
#pragma unroll
    for (int in = 0; in < 4; in++)
#pragma unroll
      for (int r = 0; r < 4; r++)
        C[(size_t)(m0 + wm + im * 16 + quad * 4 + r) * CD + n0 + wn + in * 16 + l15] =
            acc[im][in][r];
}

// Per-row entmax on register scores s[0..31] (col = 64t + lane), NEGS = invalid.
// Bit-identical arithmetic order to the round-2/3 passing version.
__device__ __forceinline__ float entmax_row(float (&s)[32], int n) {
  float ssum = 0.f;
#pragma unroll
  for (int t = 0; t < 32; t++)
    if (s[t] > -1e29f) ssum += s[t];
  ssum = wave_sum(ssum);

  float tau = (ssum - 1.f) / (float)n;
  int cnt = n;
  for (int it = 0; it < 1024; it++) {
    float cs = 0.f, cn = 0.f;
#pragma unroll
    for (int t = 0; t < 32; t++) {
      const float sv = s[t];
      if (sv > tau) { cs += sv; cn += 1.f; }  // NEGS never > tau
    }
    cs = wave_sum(cs);
    cn = wave_sum(cn);
    const int newcnt = (int)cn;
    tau = (cs - 1.f) / cn;
    if (newcnt == cnt) break;
    cnt = newcnt;
  }

  // Reference quirk: tau_star uses the FULL masked row sum, not the top-k sum.
  const float tau_star = (ssum - 1.f) / (float)cnt;
  float psum = 0.f;
#pragma unroll
  for (int t = 0; t < 32; t++) {
    float p = s[t] - tau_star;
    p = p > 0.f ? p : 0.f;
    s[t] = p;
    psum += p;
  }
  psum = wave_sum(psum);
  return 1.f / (psum + 1e-10f);
}

// WG = 256 thr (4 waves) x (head h, 16 query rows); wave w owns rows q0+4w..+3.
// launch_bounds(256,1): VGPR cap 512 so the 4x32 score array STAYS IN REGISTERS.
// Each staged K/V tile read feeds 4 rows -> half the LDS reads/row of round 3.
__global__ __launch_bounds__(256, 1) void attn_entmax4(
    const float* __restrict__ q, const float* __restrict__ k,
    const float* __restrict__ v, short* __restrict__ oh, short* __restrict__ ol) {
  __shared__ float KT[64][68];  // 17.4 KB; b128 reads conflict-free (8-lane phases)

  const int tid = threadIdx.x, lane = tid & 63, wave = tid >> 6;
  const int h = blockIdx.y, q0 = blockIdx.x * 16;
  const int col0 = h * CHD;
  const int r0 = q0 + wave * 4;                 // rows r0..r0+3
  const int ntiles = (q0 + 79) >> 6;            // cols 0..q0+15 (WG-uniform)

  float qr[4], s[4][32];
#pragma unroll
  for (int i = 0; i < 4; i++)
    qr[i] = q[(size_t)(r0 + i) * CD + col0 + lane];

  // ---- Phase 1: scores ----
#pragma unroll
  for (int jt = 0; jt < 32; jt++) {
    if (jt < ntiles) {
      const int j0 = jt * 64;
#pragma unroll
      for (int i = 0; i < 4; i++) {  // stage 64x64 fp32 K tile, b128
        const int fidx = i * 256 + tid;
        const int jr = fidx >> 4, c4 = (fidx & 15) * 4;
        *reinterpret_cast<float4*>(&KT[jr][c4]) =
            *reinterpret_cast<const float4*>(&k[(size_t)(j0 + jr) * CD + col0 + c4]);
      }
      __syncthreads();
      float a[4] = {0.f, 0.f, 0.f, 0.f};
#pragma unroll
      for (int c = 0; c < 16; c++) {
        const float4 kv = *reinterpret_cast<const float4*>(&KT[lane][c * 4]);
        const float ke[4] = {kv.x, kv.y, kv.z, kv.w};
#pragma unroll
        for (int e = 0; e < 4; e++) {  // k ascending: same order as round 2/3
#pragma unroll
          for (int i = 0; i < 4; i++)
            a[i] = fmaf(rl_f(qr[i], c * 4 + e), ke[e], a[i]);
        }
      }
      const int col = j0 + lane;
#pragma unroll
      for (int i = 0; i < 4; i++)
        s[i][jt] = (col <= r0 + i) ? a[i] * 0.125f : NEGS;
      __syncthreads();
    } else {
#pragma unroll
      for (int i = 0; i < 4; i++) s[i][jt] = NEGS;
    }
  }

  // ---- Phase 2: entmax (registers + wave shuffles only) ----
  float inv[4];
#pragma unroll
  for (int i = 0; i < 4; i++) inv[i] = entmax_row(s[i], r0 + i + 1);

  // ---- Phase 3: p @ V ----
  float acc[4] = {0.f, 0.f, 0.f, 0.f};
#pragma unroll
  for (int jt = 0; jt < 32; jt++) {
    if (jt < ntiles) {
      const int j0 = jt * 64;
#pragma unroll
      for (int i = 0; i < 4; i++) {  // stage 64x64 fp32 V tile
        const int fidx = i * 256 + tid;
        const int jr = fidx >> 4, c4 = (fidx & 15) * 4;
        *reinterpret_cast<float4*>(&KT[jr][c4]) =
            *reinterpret_cast<const float4*>(&v[(size_t)(j0 + jr) * CD + col0 + c4]);
      }
      __syncthreads();
      int lim = r0 + 3 - j0 + 1;  // wave-uniform; p==0 pads shorter rows
      lim = lim < 0 ? 0 : (lim > 64 ? 64 : lim);
      for (int j = 0; j < lim; j++) {
        const float vv = KT[j][lane];  // row read: 2-way -> free
#pragma unroll
        for (int i = 0; i < 4; i++)
          acc[i] = fmaf(rl_f(s[i][jt], j), vv, acc[i]);
      }
      __syncthreads();
    }
  }

  // ---- Epilogue: split o into bf16 hi/lo planes for the Wo MFMA GEMM ----
#pragma unroll
  for (int i = 0; i < 4; i++) {
    const float o = acc[i] * inv[i];
    __hip_bfloat16 bh = __float2bfloat16(o);
    __hip_bfloat16 bl = __float2bfloat16(o - __bfloat162float(bh));
    oh[(size_t)(r0 + i) * CD + col0 + lane] = __builtin_bit_cast(short, bh);
    ol[(size_t)(r0 + i) * CD + col0 + lane] = __builtin_bit_cast(short, bl);
  }
}

extern "C" void kernel_launch(void* const* d_in, const int* in_sizes, int n_in,
                              void* d_out, int out_size, void* d_ws, size_t ws_size,
                              hipStream_t stream) {
  const float* x  = (const float*)d_in[0];
  const float* Wq = (const float*)d_in[1];
  const float* Wk = (const float*)d_in[2];
  const float* Wv = (const float*)d_in[3];
  const float* Wo = (const float*)d_in[4];
  float* out = (float*)d_out;

  // Workspace layout (56 MB total)
  char* ws = (char*)d_ws;
  float* qf  = (float*)(ws + (0ull  << 20));  // 8 MB fp32 q
  float* kf  = (float*)(ws + (8ull  << 20));  // 8 MB fp32 k
  float* vf  = (float*)(ws + (16ull << 20));  // 8 MB fp32 v
  short* xh  = (short*)(ws + (24ull << 20));  // 4 MB
  short* xl  = (short*)(ws + (28ull << 20));  // 4 MB
  short* wqh = (short*)(ws + (32ull << 20));  // 2 MB each below
  short* wql = (short*)(ws + (34ull << 20));
  short* wkh = (short*)(ws + (36ull << 20));
  short* wkl = (short*)(ws + (38ull << 20));
  short* wvh = (short*)(ws + (40ull << 20));
  short* wvl = (short*)(ws + (42ull << 20));
  short* woh = (short*)(ws + (44ull << 20));
  short* wol = (short*)(ws + (46ull << 20));
  short* oh  = (short*)(ws + (48ull << 20));  // 4 MB
  short* ol  = (short*)(ws + (52ull << 20));  // 4 MB

  // Split fp32 inputs into bf16 hi/lo planes
  split_bf16<<<2048, 256, 0, stream>>>(x,  xh,  xl,  (CL * CD) / 4);
  split_bf16<<<1024, 256, 0, stream>>>(Wq, wqh, wql, (CD * CD) / 4);
  split_bf16<<<1024, 256, 0, stream>>>(Wk, wkh, wkl, (CD * CD) / 4);
  split_bf16<<<1024, 256, 0, stream>>>(Wv, wvh, wvl, (CD * CD) / 4);
  split_bf16<<<1024, 256, 0, stream>>>(Wo, woh, wol, (CD * CD) / 4);

  // Fused QKV: grid.x = 24 -> sel = x>>3 picks (Wq,qf)/(Wk,kf)/(Wv,vf)
  gemm128_split<<<dim3(24, CL / 128), 256, 0, stream>>>(
      xh, xl, wqh, wql, wkh, wkl, wvh, wvl, qf, kf, vf);

  attn_entmax4<<<dim3(CL / 16, CH), 256, 0, stream>>>(qf, kf, vf, oh, ol);

  // Wo: grid.x = 8 -> sel = 0
  gemm128_split<<<dim3(8, CL / 128), 256, 0, stream>>>(
      oh, ol, woh, wol, woh, wol, woh, wol, out, out, out);
}